// Round 1
// baseline (342.988 us; speedup 1.0000x reference)
//
#include <hip/hip_runtime.h>
#include <hip/hip_bf16.h>

using bf16 = __bf16;
using bf16x4 = __attribute__((ext_vector_type(4))) __bf16;
using bf16x8 = __attribute__((ext_vector_type(8))) __bf16;
using f32x4 = __attribute__((ext_vector_type(4))) float;

#define LOG2E 1.4426950408889634f

// ---------------- prep: fp32 -> bf16 elementwise ----------------
__global__ __launch_bounds__(256) void cvt_kernel(const float4* __restrict__ in,
                                                  bf16x4* __restrict__ out, int n4) {
  int g = blockIdx.x * blockDim.x + threadIdx.x;
  if (g < n4) {
    float4 v = in[g];
    bf16x4 o = {(bf16)v.x, (bf16)v.y, (bf16)v.z, (bf16)v.w};
    out[g] = o;
  }
}

// ---------------- prep: W[k][n] fp32 -> Wt[n][k] bf16 ----------------
__global__ __launch_bounds__(256) void transpose_kernel(const float* __restrict__ w,
                                                        bf16* __restrict__ wt) {
  __shared__ float tile[32][33];
  int k0 = blockIdx.y * 32, n0 = blockIdx.x * 32;
  int tx = threadIdx.x, ty = threadIdx.y;
#pragma unroll
  for (int i = 0; i < 4; i++)
    tile[ty + i * 8][tx] = w[(size_t)(k0 + ty + i * 8) * 1024 + n0 + tx];
  __syncthreads();
#pragma unroll
  for (int i = 0; i < 4; i++)
    wt[(size_t)(n0 + ty + i * 8) * 1024 + k0 + tx] = (bf16)tile[tx][ty + i * 8];
}

// ---------------- GEMM: C[m][n] = A[m][k] * Wt[n][k]^T + bias ----------------
// A: [M][1024] bf16 ; Bt: [1024][1024] bf16 (n-major, k contiguous)
// MODE 0: out bf16, head-split [(b*16+h)*2048 + t][64]
// MODE 1: out bf16, V-transposed [((b*16+h)*64 + d)][2048] (col s)
// MODE 2: out fp32, plain [m][1024]
template <int MODE>
__global__ __launch_bounds__(256) void gemm_kernel(const bf16* __restrict__ A,
                                                   const bf16* __restrict__ Bt,
                                                   const float* __restrict__ bias,
                                                   void* __restrict__ outp) {
  constexpr int K = 1024;
  __shared__ __align__(16) char smem[34816];
  bf16(*As)[40] = (bf16(*)[40])smem;
  bf16(*Bs)[40] = (bf16(*)[40])(smem + 10240);
  bf16(*Cs)[136] = (bf16(*)[136])smem;

  const int tid = threadIdx.x;
  const int lane = tid & 63;
  const int w = tid >> 6;
  const int wr = w >> 1, wc = w & 1;
  const int m0 = blockIdx.y * 128, n0 = blockIdx.x * 128;
  const int fr = lane & 15, fg = (lane >> 4) * 8;

  f32x4 acc[4][4] = {};

  const int srow = tid >> 2;             // 0..63
  const int kc = (tid & 3) * 8;          // 0,8,16,24
  const int arow = m0 + srow, brow = n0 + srow;

  bf16x8 ra0, ra1, rb0, rb1;
  ra0 = *(const bf16x8*)&A[(size_t)arow * K + kc];
  ra1 = *(const bf16x8*)&A[(size_t)(arow + 64) * K + kc];
  rb0 = *(const bf16x8*)&Bt[(size_t)brow * K + kc];
  rb1 = *(const bf16x8*)&Bt[(size_t)(brow + 64) * K + kc];

  for (int k0 = 0; k0 < K; k0 += 32) {
    __syncthreads();
    *(bf16x8*)&As[srow][kc] = ra0;
    *(bf16x8*)&As[srow + 64][kc] = ra1;
    *(bf16x8*)&Bs[srow][kc] = rb0;
    *(bf16x8*)&Bs[srow + 64][kc] = rb1;
    if (k0 + 32 < K) {
      int kn = k0 + 32 + kc;
      ra0 = *(const bf16x8*)&A[(size_t)arow * K + kn];
      ra1 = *(const bf16x8*)&A[(size_t)(arow + 64) * K + kn];
      rb0 = *(const bf16x8*)&Bt[(size_t)brow * K + kn];
      rb1 = *(const bf16x8*)&Bt[(size_t)(brow + 64) * K + kn];
    }
    __syncthreads();
    bf16x8 af[4], bfr[4];
#pragma unroll
    for (int mi = 0; mi < 4; mi++)
      af[mi] = *(const bf16x8*)&As[wr * 64 + mi * 16 + fr][fg];
#pragma unroll
    for (int ni = 0; ni < 4; ni++)
      bfr[ni] = *(const bf16x8*)&Bs[wc * 64 + ni * 16 + fr][fg];
#pragma unroll
    for (int mi = 0; mi < 4; mi++)
#pragma unroll
      for (int ni = 0; ni < 4; ni++)
        acc[mi][ni] =
            __builtin_amdgcn_mfma_f32_16x16x32_bf16(af[mi], bfr[ni], acc[mi][ni], 0, 0, 0);
  }

  // bias
  float bv[4];
#pragma unroll
  for (int ni = 0; ni < 4; ni++) bv[ni] = bias[n0 + wc * 64 + ni * 16 + fr];
#pragma unroll
  for (int mi = 0; mi < 4; mi++)
#pragma unroll
    for (int ni = 0; ni < 4; ni++)
#pragma unroll
      for (int j = 0; j < 4; j++) acc[mi][ni][j] += bv[ni];

  if (MODE == 2) {
    float* O = (float*)outp;
#pragma unroll
    for (int mi = 0; mi < 4; mi++)
#pragma unroll
      for (int ni = 0; ni < 4; ni++)
#pragma unroll
        for (int j = 0; j < 4; j++) {
          int row = m0 + wr * 64 + mi * 16 + (lane >> 4) * 4 + j;
          int col = n0 + wc * 64 + ni * 16 + fr;
          O[(size_t)row * 1024 + col] = acc[mi][ni][j];
        }
    return;
  }

  __syncthreads();  // done with As/Bs staging area
#pragma unroll
  for (int mi = 0; mi < 4; mi++) {
    int r = wr * 64 + mi * 16 + (lane >> 4) * 4;
#pragma unroll
    for (int ni = 0; ni < 4; ni++) {
      int c = wc * 64 + ni * 16 + fr;
#pragma unroll
      for (int j = 0; j < 4; j++) Cs[r + j][c] = (bf16)acc[mi][ni][j];
    }
  }
  __syncthreads();

  bf16* O = (bf16*)outp;
  if (MODE == 0) {
    int row = tid >> 1, ch = (tid & 1) * 64;
    int rg = m0 + row;
    int b = rg >> 11, t_ = rg & 2047;
    int c0 = n0 + ch;
    int h = c0 >> 6;
    bf16* dst = O + ((size_t)(b * 16 + h) * 2048 + t_) * 64;
#pragma unroll
    for (int i = 0; i < 8; i++) *(bf16x8*)&dst[i * 8] = *(const bf16x8*)&Cs[row][ch + i * 8];
  } else {  // MODE 1: V^T
    int colL = tid >> 1, sh = (tid & 1) * 64;
    int cg = n0 + colL;
    int h = cg >> 6, d = cg & 63;
    int rg = m0 + sh;
    int b = rg >> 11, s_ = rg & 2047;
    bf16* dst = O + ((size_t)((b * 16 + h) * 64 + d)) * 2048 + s_;
#pragma unroll
    for (int i = 0; i < 8; i++) {
      bf16x8 v;
#pragma unroll
      for (int jj = 0; jj < 8; jj++) v[jj] = Cs[sh + i * 8 + jj][colL];
      *(bf16x8*)&dst[i * 8] = v;
    }
  }
}

// ---------------- flash attention ----------------
// Q: [bh*2048 + t][64], K: [bh*2048 + s][64], Vt: [bh*64 + d][2048], Y: [b*2048+t][1024]
__global__ __launch_bounds__(256) void attn_kernel(const bf16* __restrict__ Q,
                                                   const bf16* __restrict__ Kc,
                                                   const bf16* __restrict__ Vt,
                                                   bf16* __restrict__ Y) {
  const int qt = blockIdx.x, bh = blockIdx.y;
  const int tid = threadIdx.x, lane = tid & 63, w = tid >> 6;
  const int lr = lane & 15, lg = lane >> 4;
  const int q0 = qt * 64 + w * 16;
  __shared__ __align__(16) bf16 Plds[4][16][40];

  bf16x8 qf0, qf1;
  {
    const bf16* qb = Q + ((size_t)bh * 2048 + q0 + lr) * 64 + lg * 8;
    qf0 = *(const bf16x8*)qb;
    qf1 = *(const bf16x8*)(qb + 32);
  }

  f32x4 yacc[4] = {};
  float mrow[4], lrow[4];
#pragma unroll
  for (int j = 0; j < 4; j++) {
    mrow[j] = -__builtin_inff();
    lrow[j] = 0.0f;
  }

  const int nchunk = 2 * qt + 2;
  for (int c = 0; c < nchunk; c++) {
    const int sbase = c * 32;
    f32x4 sc[2];
#pragma unroll
    for (int half = 0; half < 2; half++) {
      const bf16* kb = Kc + ((size_t)bh * 2048 + sbase + half * 16 + lr) * 64 + lg * 8;
      f32x4 z = {};
      z = __builtin_amdgcn_mfma_f32_16x16x32_bf16(qf0, *(const bf16x8*)kb, z, 0, 0, 0);
      z = __builtin_amdgcn_mfma_f32_16x16x32_bf16(qf1, *(const bf16x8*)(kb + 32), z, 0, 0, 0);
      sc[half] = z;
    }
    // scale + causal mask
#pragma unroll
    for (int half = 0; half < 2; half++) {
      int s_g = sbase + half * 16 + lr;
#pragma unroll
      for (int j = 0; j < 4; j++) {
        int q_g = q0 + lg * 4 + j;
        float z = sc[half][j] * 0.125f;
        sc[half][j] = (s_g <= q_g) ? z : -__builtin_inff();
      }
    }
    // online softmax per row (reg j), row-reduce across 16-lane groups
#pragma unroll
    for (int j = 0; j < 4; j++) {
      float vmax = fmaxf(sc[0][j], sc[1][j]);
#pragma unroll
      for (int off = 1; off < 16; off <<= 1) vmax = fmaxf(vmax, __shfl_xor(vmax, off));
      float mnew = fmaxf(mrow[j], vmax);
      float cf = exp2f((mrow[j] - mnew) * LOG2E);
      mrow[j] = mnew;
      float p0 = exp2f((sc[0][j] - mnew) * LOG2E);
      float p1 = exp2f((sc[1][j] - mnew) * LOG2E);
      float rs = p0 + p1;
#pragma unroll
      for (int off = 1; off < 16; off <<= 1) rs += __shfl_xor(rs, off);
      lrow[j] = lrow[j] * cf + rs;
#pragma unroll
      for (int nf = 0; nf < 4; nf++) yacc[nf][j] *= cf;
      Plds[w][lg * 4 + j][lr] = (bf16)p0;
      Plds[w][lg * 4 + j][16 + lr] = (bf16)p1;
    }
    bf16x8 pa = *(const bf16x8*)&Plds[w][lr][lg * 8];
    const bf16* vb = Vt + ((size_t)bh * 64 + lr) * 2048 + sbase + lg * 8;
#pragma unroll
    for (int nf = 0; nf < 4; nf++) {
      bf16x8 vf = *(const bf16x8*)(vb + (size_t)nf * 16 * 2048);
      yacc[nf] = __builtin_amdgcn_mfma_f32_16x16x32_bf16(pa, vf, yacc[nf], 0, 0, 0);
    }
  }

  float inv[4];
#pragma unroll
  for (int j = 0; j < 4; j++) inv[j] = 1.0f / lrow[j];
  const int b = bh >> 4, h = bh & 15;
#pragma unroll
  for (int nf = 0; nf < 4; nf++)
#pragma unroll
    for (int j = 0; j < 4; j++) {
      int q_g = q0 + lg * 4 + j;
      Y[((size_t)b * 2048 + q_g) * 1024 + h * 64 + nf * 16 + lr] = (bf16)(yacc[nf][j] * inv[j]);
    }
}

extern "C" void kernel_launch(void* const* d_in, const int* in_sizes, int n_in,
                              void* d_out, int out_size, void* d_ws, size_t ws_size,
                              hipStream_t stream) {
  const float* x = (const float*)d_in[0];
  const float* ctx = (const float*)d_in[1];
  const float* q_w = (const float*)d_in[2];
  const float* q_b = (const float*)d_in[3];
  const float* k_w = (const float*)d_in[4];
  const float* k_b = (const float*)d_in[5];
  const float* v_w = (const float*)d_in[6];
  const float* v_b = (const float*)d_in[7];
  const float* o_w = (const float*)d_in[8];
  const float* o_b = (const float*)d_in[9];

  char* ws = (char*)d_ws;
  const size_t MB = 1024 * 1024;
  bf16* xb = (bf16*)(ws + 0);
  bf16* cb = (bf16*)(ws + 8 * MB);
  bf16* qwt = (bf16*)(ws + 16 * MB);
  bf16* kwt = (bf16*)(ws + 18 * MB);
  bf16* vwt = (bf16*)(ws + 20 * MB);
  bf16* owt = (bf16*)(ws + 22 * MB);
  bf16* Qws = (bf16*)(ws + 24 * MB);
  bf16* Kws = (bf16*)(ws + 32 * MB);
  bf16* Vt = (bf16*)(ws + 40 * MB);
  bf16* Yws = (bf16*)(ws + 48 * MB);

  cvt_kernel<<<4096, 256, 0, stream>>>((const float4*)x, (bf16x4*)xb, 1048576);
  cvt_kernel<<<4096, 256, 0, stream>>>((const float4*)ctx, (bf16x4*)cb, 1048576);

  dim3 tb(32, 8), tg(32, 32);
  transpose_kernel<<<tg, tb, 0, stream>>>(q_w, qwt);
  transpose_kernel<<<tg, tb, 0, stream>>>(k_w, kwt);
  transpose_kernel<<<tg, tb, 0, stream>>>(v_w, vwt);
  transpose_kernel<<<tg, tb, 0, stream>>>(o_w, owt);

  dim3 gg(8, 32);
  gemm_kernel<0><<<gg, 256, 0, stream>>>(xb, qwt, q_b, (void*)Qws);
  gemm_kernel<0><<<gg, 256, 0, stream>>>(cb, kwt, k_b, (void*)Kws);
  gemm_kernel<1><<<gg, 256, 0, stream>>>(cb, vwt, v_b, (void*)Vt);

  attn_kernel<<<dim3(32, 32), 256, 0, stream>>>(Qws, Kws, Vt, Yws);

  gemm_kernel<2><<<gg, 256, 0, stream>>>(Yws, owt, o_b, d_out);
}